// Round 7
// baseline (3101.743 us; speedup 1.0000x reference)
//
#include <hip/hip_runtime.h>
#include <cstddef>
#include <cstdint>

#define BN_EPS 1e-5f

typedef float f4 __attribute__((ext_vector_type(4)));

// ---------------------------------------------------------------------------
// Weight transpose: W[27][CIN][COUT] -> Wt[k][ci/4][co][4] so a lane (=co)
// loads 4 consecutive ci as one coalesced dwordx4.
// ---------------------------------------------------------------------------
template<int CIN, int COUT>
__global__ __launch_bounds__(256)
void wtrans(const float* __restrict__ W, float* __restrict__ Wt)
{
    const int t = blockIdx.x * 256 + threadIdx.x;
    constexpr int TOTAL = 27 * (CIN / 4) * COUT;
    if (t >= TOTAL) return;
    const int co = t % COUT;
    const int rest = t / COUT;
    const int c4 = rest % (CIN / 4);
    const int k  = rest / (CIN / 4);
    f4 v;
    #pragma unroll
    for (int u = 0; u < 4; ++u)
        v[u] = W[((size_t)k * CIN + c4 * 4 + u) * COUT + co];
    *(f4*)(Wt + (size_t)t * 4) = v;
}

// ---------------------------------------------------------------------------
// Sparse conv for COUT in {64,128}. Block = 256 = 4 waves; each wave handles
// R=16 consecutive output rows (lane = co, CPL = COUT/64 channels per lane).
// Structure = round-5 winner (fully-unrolled ci loop, zrow-unguarded x loads
// that compile to batched s_loads) + active-k ctz loop (dead offsets cost 0,
// replaces 27x16 cross-lane shfls with SALU readlane on active k only) +
// Wt dwordx4 weight loads (4x fewer W VMEM issues) + R=16 (2x W-slice
// amortization vs R=8; W L1 traffic per wave-k is 32KB regardless of valid
// row count, so rows/wave is the only lever on it).
// ---------------------------------------------------------------------------
template<int CIN, int CINA, int COUT, int R>
__global__ __launch_bounds__(256)
void sconv_big(const float* __restrict__ xA, const float* __restrict__ xB,
               const float* __restrict__ Wt, const int* __restrict__ map,
               int Nout, float* __restrict__ out, const float* __restrict__ zrow)
{
    constexpr int CINB = CIN - CINA;
    constexpr int CPL  = COUT / 64;
    const int lane = threadIdx.x & 63;
    const int wave = threadIdx.x >> 6;
    const int row0 = (blockIdx.x * 4 + wave) * R;

    // lane-parallel map prefetch: lane k<27 holds map[k][row0+r] in mk[r]
    int mk[R];
    bool anyv = false;
    #pragma unroll
    for (int r = 0; r < R; ++r) {
        const int j = row0 + r;
        mk[r] = (lane < 27 && j < Nout) ? map[(size_t)lane * Nout + j] : -1;
        anyv |= (mk[r] >= 0);
    }
    unsigned long long act = __ballot(anyv);  // bit k = offset k has >=1 valid row

    float acc[R][CPL];
    #pragma unroll
    for (int r = 0; r < R; ++r)
        #pragma unroll
        for (int c = 0; c < CPL; ++c) acc[r][c] = 0.f;

    while (act) {
        const int k = (int)__builtin_ctzll(act);
        act &= act - 1;

        int m[R];
        const float* pA[R];
        const float* pB[R];
        #pragma unroll
        for (int r = 0; r < R; ++r) {
            m[r] = __builtin_amdgcn_readlane(mk[r], k);   // uniform SGPR
            const bool v = (m[r] >= 0);
            pA[r] = v ? (xA + (size_t)m[r] * CINA) : zrow;  // uniform cselect
            if constexpr (CINB > 0)
                pB[r] = v ? (xB + (size_t)m[r] * CINB) : zrow;
        }

        const float* Wk = Wt + (size_t)k * CIN * COUT;

        #pragma unroll
        for (int t = 0; t < CIN / 8; ++t) {
            const int ci = t * 8;
            // ---- W tile: 2 coalesced dwordx4 per CPL ----
            f4 w0[CPL], w1[CPL];
            #pragma unroll
            for (int c = 0; c < CPL; ++c) {
                w0[c] = *(const f4*)(Wk + ((size_t)(2 * t) * COUT
                                           + c * 64 + lane) * 4);
                w1[c] = *(const f4*)(Wk + ((size_t)(2 * t + 1) * COUT
                                           + c * 64 + lane) * 4);
            }

            // ---- unguarded batched x loads (zrow -> reads 0 for invalid) --
            f4 xv0[R], xv1[R];
            #pragma unroll
            for (int r = 0; r < R; ++r) {
                const float* p;
                if constexpr (CINB > 0)
                    p = (ci < CINA) ? (pA[r] + ci) : (pB[r] + (ci - CINA));
                else
                    p = pA[r] + ci;
                xv0[r] = *(const f4*)p;
                xv1[r] = *(const f4*)(p + 4);
            }

            // ---- guarded FMA blocks (wave-uniform scalar branches) ----
            #pragma unroll
            for (int r = 0; r < R; ++r) {
                if (m[r] >= 0) {
                    #pragma unroll
                    for (int u = 0; u < 4; ++u)
                        #pragma unroll
                        for (int c = 0; c < CPL; ++c) {
                            acc[r][c] = fmaf(xv0[r][u], w0[c][u], acc[r][c]);
                            acc[r][c] = fmaf(xv1[r][u], w1[c][u], acc[r][c]);
                        }
                }
            }
        }
    }

    #pragma unroll
    for (int r = 0; r < R; ++r) {
        const int j = row0 + r;
        if (j < Nout) {
            #pragma unroll
            for (int c = 0; c < CPL; ++c)
                out[(size_t)j * COUT + c * 64 + lane] = acc[r][c];
        }
    }
}

// ---------------------------------------------------------------------------
// conv0: CIN=16, COUT=32. One row per half-wave; block 256 = 8 rows.
// Wt weight loads (dwordx4); zrow-unguarded x (only 1 row / half-wave).
// ---------------------------------------------------------------------------
__global__ __launch_bounds__(256)
void sconv0(const float* __restrict__ x, const float* __restrict__ Wt,
            const int* __restrict__ map, int N, float* __restrict__ out,
            const float* __restrict__ zrow)
{
    const int tid  = threadIdx.x;
    const int lane = tid & 63;
    const int l32  = tid & 31;
    const int co   = l32;
    const int j    = blockIdx.x * 8 + (tid >> 5);

    int mk = (l32 < 27 && j < N) ? map[(size_t)l32 * N + j] : -1;

    float a0 = 0.f, a1 = 0.f, a2 = 0.f, a3 = 0.f;
    for (int k = 0; k < 27; ++k) {
        const int m = __shfl(mk, (lane & 32) + k);
        if (__ballot(m >= 0) == 0ull) continue;
        const float* xr = (m >= 0) ? (x + (size_t)m * 16) : zrow;
        const float* wk = Wt + (size_t)k * 16 * 32;
        f4 w0 = *(const f4*)(wk + (0 * 32 + co) * 4);
        f4 w1 = *(const f4*)(wk + (1 * 32 + co) * 4);
        f4 w2 = *(const f4*)(wk + (2 * 32 + co) * 4);
        f4 w3 = *(const f4*)(wk + (3 * 32 + co) * 4);
        f4 x0 = *(const f4*)(xr);
        f4 x1 = *(const f4*)(xr + 4);
        f4 x2 = *(const f4*)(xr + 8);
        f4 x3 = *(const f4*)(xr + 12);
        #pragma unroll
        for (int u = 0; u < 4; ++u) {
            a0 = fmaf(x0[u], w0[u], a0);
            a1 = fmaf(x1[u], w1[u], a1);
            a2 = fmaf(x2[u], w2[u], a2);
            a3 = fmaf(x3[u], w3[u], a3);
        }
    }
    if (j < N) out[(size_t)j * 32 + co] = (a0 + a1) + (a2 + a3);
}

// ---------------------------------------------------------------------------
// conv0t: x = concat(d1[*,64], s1[*,32]), COUT=2. 32 lanes cooperate per row.
// ---------------------------------------------------------------------------
__global__ __launch_bounds__(256)
void sconv0t(const float* __restrict__ d1, const float* __restrict__ s1,
             const float* __restrict__ W /*[27,96,2]*/,
             const int* __restrict__ map, int N, float* __restrict__ out,
             const float* __restrict__ zrow)
{
    const int tid  = threadIdx.x;
    const int lane = tid & 63;
    const int l32  = tid & 31;
    const int j    = blockIdx.x * 8 + (tid >> 5);

    int mk = (l32 < 27 && j < N) ? map[(size_t)l32 * N + j] : -1;

    float a0 = 0.f, a1 = 0.f;
    for (int k = 0; k < 27; ++k) {
        const int m = __shfl(mk, (lane & 32) + k);
        if (__ballot(m >= 0) == 0ull) continue;
        const float* p1 = (m >= 0) ? (d1 + (size_t)m * 64) : zrow;
        const float* p2 = (m >= 0) ? (s1 + (size_t)m * 32) : zrow;
        const float* w = W + (size_t)k * 96 * 2;
        const float x0 = p1[l32];
        const float x1 = p1[l32 + 32];
        const float x2 = p2[l32];
        a0 = fmaf(x0, w[l32 * 2 + 0], a0);
        a1 = fmaf(x0, w[l32 * 2 + 1], a1);
        a0 = fmaf(x1, w[(l32 + 32) * 2 + 0], a0);
        a1 = fmaf(x1, w[(l32 + 32) * 2 + 1], a1);
        a0 = fmaf(x2, w[(l32 + 64) * 2 + 0], a0);
        a1 = fmaf(x2, w[(l32 + 64) * 2 + 1], a1);
    }
    #pragma unroll
    for (int off = 1; off < 32; off <<= 1) {
        a0 += __shfl_xor(a0, off, 32);
        a1 += __shfl_xor(a1, off, 32);
    }
    if (l32 == 0 && j < N) {
        out[(size_t)j * 2 + 0] = a0;
        out[(size_t)j * 2 + 1] = a1;
    }
}

// ---------------------------------------------------------------------------
// BN pass 1: per-channel sum and sum-of-squares -> atomicAdd into sums[2*C]
// ---------------------------------------------------------------------------
template<int C>
__global__ __launch_bounds__(256)
void bn_reduce_kernel(const float* __restrict__ x, int N,
                      float* __restrict__ sums)
{
    constexpr int RG = 256 / C;
    const int tid = threadIdx.x;
    const int c   = tid % C;
    const int rg  = tid / C;
    float s = 0.f, s2 = 0.f;
    for (int j = blockIdx.x * RG + rg; j < N; j += gridDim.x * RG) {
        const float v = x[(size_t)j * C + c];
        s += v;
        s2 += v * v;
    }
    __shared__ float sh[2 * 256];
    sh[tid] = s;
    sh[256 + tid] = s2;
    __syncthreads();
    for (int stride = 128; stride >= C; stride >>= 1) {
        if (tid < stride) {
            sh[tid] += sh[tid + stride];
            sh[256 + tid] += sh[256 + tid + stride];
        }
        __syncthreads();
    }
    if (tid < C) {
        atomicAdd(&sums[c], sh[tid]);
        atomicAdd(&sums[C + c], sh[256 + tid]);
    }
}

// ---------------------------------------------------------------------------
// BN pass 2: x = relu((x - mu) * rsqrt(var + eps) * g + b), in place
// ---------------------------------------------------------------------------
template<int C>
__global__ __launch_bounds__(256)
void bn_apply_kernel(float* __restrict__ x, int N,
                     const float* __restrict__ sums,
                     const float* __restrict__ g, const float* __restrict__ b)
{
    const int tid = blockIdx.x * blockDim.x + threadIdx.x;
    const int c = tid % C;
    const float invN = 1.0f / (float)N;
    const float mean = sums[c] * invN;
    float var = sums[C + c] * invN - mean * mean;
    var = fmaxf(var, 0.f);
    const float sc = g[c] * rsqrtf(var + BN_EPS);
    const float sh = b[c] - mean * sc;
    const int rows_stride = (gridDim.x * blockDim.x) / C;
    for (int j = tid / C; j < N; j += rows_stride) {
        const size_t i = (size_t)j * C + c;
        const float v = fmaf(x[i], sc, sh);
        x[i] = v > 0.f ? v : 0.f;
    }
}

// ---------------------------------------------------------------------------
extern "C" void kernel_launch(void* const* d_in, const int* in_sizes, int n_in,
                              void* d_out, int out_size, void* d_ws, size_t ws_size,
                              hipStream_t stream)
{
    const float* feats = (const float*)d_in[0];
    const float* W0  = (const float*)d_in[1];
    const float* g0  = (const float*)d_in[2];
    const float* b0  = (const float*)d_in[3];
    const float* W1  = (const float*)d_in[4];
    const float* g1  = (const float*)d_in[5];
    const float* b1  = (const float*)d_in[6];
    const float* W2  = (const float*)d_in[7];
    const float* g2  = (const float*)d_in[8];
    const float* b2  = (const float*)d_in[9];
    const float* W2t = (const float*)d_in[10];
    const float* g2t = (const float*)d_in[11];
    const float* b2t = (const float*)d_in[12];
    const float* W1t = (const float*)d_in[13];
    const float* g1t = (const float*)d_in[14];
    const float* b1t = (const float*)d_in[15];
    const float* W0t = (const float*)d_in[16];
    const int* map0  = (const int*)d_in[17];
    const int* map1  = (const int*)d_in[18];
    const int* map2  = (const int*)d_in[19];
    const int* map2t = (const int*)d_in[20];
    const int* map1t = (const int*)d_in[21];
    const int* map0t = (const int*)d_in[22];

    const int N0 = in_sizes[0] / 16;
    const int N1 = in_sizes[18] / 27;
    const int N2 = in_sizes[19] / 27;

    float* ws = (float*)d_ws;
    float* y0 = ws;                      // [N0,32]  s1
    float* y1 = y0 + (size_t)N0 * 32;    // [N1,64]  s2
    float* y2 = y1 + (size_t)N1 * 64;    // [N2,128] s4
    float* y3 = y2 + (size_t)N2 * 128;   // [N1,64]  d2
    float* y4 = y3 + (size_t)N1 * 64;    // [N0,64]  d1
    float* sums  = y4 + (size_t)N0 * 64; // BN accumulators (704 floats)
    float* sums0 = sums;        // 2*32
    float* sums1 = sums + 64;   // 2*64
    float* sums2 = sums + 192;  // 2*128
    float* sums3 = sums + 448;  // 2*64
    float* sums4 = sums + 576;  // 2*64
    float* zrow  = sums + 704;  // 128 zeroed floats
    // transposed weights
    float* Wt0  = zrow + 128;                   // 27*16*32
    float* Wt1  = Wt0 + 27 * 16 * 32;           // 27*32*64
    float* Wt2  = Wt1 + 27 * 32 * 64;           // 27*64*128
    float* Wt2t = Wt2 + 27 * 64 * 128;          // 27*128*64
    float* Wt1t = Wt2t + 27 * 128 * 64;         // 27*128*64

    hipMemsetAsync(sums, 0, (704 + 128) * sizeof(float), stream);

    // weight transposes (tiny)
    wtrans<16, 32><<<(27 * 4 * 32 + 255) / 256, 256, 0, stream>>>(W0, Wt0);
    wtrans<32, 64><<<(27 * 8 * 64 + 255) / 256, 256, 0, stream>>>(W1, Wt1);
    wtrans<64, 128><<<(27 * 16 * 128 + 255) / 256, 256, 0, stream>>>(W2, Wt2);
    wtrans<128, 64><<<(27 * 32 * 64 + 255) / 256, 256, 0, stream>>>(W2t, Wt2t);
    wtrans<128, 64><<<(27 * 32 * 64 + 255) / 256, 256, 0, stream>>>(W1t, Wt1t);

    // block0: feats[N0,16] -> y0[N0,32]
    sconv0<<<(N0 + 7) / 8, 256, 0, stream>>>(feats, Wt0, map0, N0, y0, zrow);
    bn_reduce_kernel<32><<<256, 256, 0, stream>>>(y0, N0, sums0);
    bn_apply_kernel<32><<<512, 256, 0, stream>>>(y0, N0, sums0, g0, b0);

    // block1: s1[N0,32] -> y1[N1,64]   (R=16 -> 64 rows/block)
    sconv_big<32, 32, 64, 16><<<(N1 + 63) / 64, 256, 0, stream>>>(
        y0, nullptr, Wt1, map1, N1, y1, zrow);
    bn_reduce_kernel<64><<<256, 256, 0, stream>>>(y1, N1, sums1);
    bn_apply_kernel<64><<<512, 256, 0, stream>>>(y1, N1, sums1, g1, b1);

    // block2: s2[N1,64] -> y2[N2,128]
    sconv_big<64, 64, 128, 16><<<(N2 + 63) / 64, 256, 0, stream>>>(
        y1, nullptr, Wt2, map2, N2, y2, zrow);
    bn_reduce_kernel<128><<<256, 256, 0, stream>>>(y2, N2, sums2);
    bn_apply_kernel<128><<<512, 256, 0, stream>>>(y2, N2, sums2, g2, b2);

    // block2_tr: s4[N2,128] -> y3[N1,64]
    sconv_big<128, 128, 64, 16><<<(N1 + 63) / 64, 256, 0, stream>>>(
        y2, nullptr, Wt2t, map2t, N1, y3, zrow);
    bn_reduce_kernel<64><<<256, 256, 0, stream>>>(y3, N1, sums3);
    bn_apply_kernel<64><<<512, 256, 0, stream>>>(y3, N1, sums3, g2t, b2t);

    // block1_tr: concat(d2,s2)[N1,128] -> y4[N0,64]
    sconv_big<128, 64, 64, 16><<<(N0 + 63) / 64, 256, 0, stream>>>(
        y3, y1, Wt1t, map1t, N0, y4, zrow);
    bn_reduce_kernel<64><<<256, 256, 0, stream>>>(y4, N0, sums4);
    bn_apply_kernel<64><<<512, 256, 0, stream>>>(y4, N0, sums4, g1t, b1t);

    // block0_tr: concat(d1,s1)[N0,96] -> out[N0,2]
    sconv0t<<<(N0 + 7) / 8, 256, 0, stream>>>(y4, y0, W0t, map0t, N0,
                                              (float*)d_out, zrow);
}

// Round 8
// 1675.262 us; speedup vs baseline: 1.8515x; 1.8515x over previous
//
#include <hip/hip_runtime.h>
#include <cstddef>
#include <cstdint>

#define BN_EPS 1e-5f

typedef float f4 __attribute__((ext_vector_type(4)));

// ---------------------------------------------------------------------------
// Weight transpose: W[27][CIN][COUT] -> Wt[k][ci/4][co][4] so a lane (=co)
// loads 4 consecutive ci as one coalesced dwordx4.
// ---------------------------------------------------------------------------
template<int CIN, int COUT>
__global__ __launch_bounds__(256)
void wtrans(const float* __restrict__ W, float* __restrict__ Wt)
{
    const int t = blockIdx.x * 256 + threadIdx.x;
    constexpr int TOTAL = 27 * (CIN / 4) * COUT;
    if (t >= TOTAL) return;
    const int co = t % COUT;
    const int rest = t / COUT;
    const int c4 = rest % (CIN / 4);
    const int k  = rest / (CIN / 4);
    f4 v;
    #pragma unroll
    for (int u = 0; u < 4; ++u)
        v[u] = W[((size_t)k * CIN + c4 * 4 + u) * COUT + co];
    *(f4*)(Wt + (size_t)t * 4) = v;
}

// ---------------------------------------------------------------------------
// Sparse conv, COUT in {64,128}. Block = 256 = 4 waves; wave handles R=8
// consecutive output rows (lane = co, CPL = COUT/64 channels per lane).
// Structure = round-5 winner: fully-unrolled ci loop; x row pointers are
// wave-uniform (readlane -> SGPR) with zrow redirect for invalid rows so the
// x loads are UNGUARDED batched s_loads (8 rows x 8ch = 64 SGPRs in flight,
// the measured sweet spot -- R=16 overflowed SGPRs and regressed 2.5x);
// FMA blocks guarded by wave-uniform scalar branches.
// + ctz active-k loop (dead offsets cost zero; no cross-lane ops per k)
// + Wt dwordx4 weights (4x fewer W VMEM issues than round 5).
// ---------------------------------------------------------------------------
template<int CIN, int CINA, int COUT>
__global__ __launch_bounds__(256)
void sconv_big(const float* __restrict__ xA, const float* __restrict__ xB,
               const float* __restrict__ Wt, const int* __restrict__ map,
               int Nout, float* __restrict__ out, const float* __restrict__ zrow)
{
    constexpr int CINB = CIN - CINA;
    constexpr int CPL  = COUT / 64;
    constexpr int R    = 8;
    const int lane = threadIdx.x & 63;
    const int wave = threadIdx.x >> 6;
    const int row0 = (blockIdx.x * 4 + wave) * R;

    // lane-parallel map prefetch: lane k<27 holds map[k][row0+r] in mk[r]
    int mk[R];
    bool anyv = false;
    #pragma unroll
    for (int r = 0; r < R; ++r) {
        const int j = row0 + r;
        mk[r] = (lane < 27 && j < Nout) ? map[(size_t)lane * Nout + j] : -1;
        anyv |= (mk[r] >= 0);
    }
    unsigned long long act = __ballot(anyv);  // bit k = offset k has >=1 valid row

    float acc[R][CPL];
    #pragma unroll
    for (int r = 0; r < R; ++r)
        #pragma unroll
        for (int c = 0; c < CPL; ++c) acc[r][c] = 0.f;

    while (act) {
        const int k = (int)__builtin_ctzll(act);
        act &= act - 1;

        int m[R];
        const float* pA[R];
        const float* pB[R];
        #pragma unroll
        for (int r = 0; r < R; ++r) {
            m[r] = __builtin_amdgcn_readlane(mk[r], k);   // uniform SGPR
            const bool v = (m[r] >= 0);
            pA[r] = v ? (xA + (size_t)m[r] * CINA) : zrow;  // uniform cselect
            if constexpr (CINB > 0)
                pB[r] = v ? (xB + (size_t)m[r] * CINB) : zrow;
        }

        const float* Wk = Wt + (size_t)k * (CIN / 4) * COUT * 4;

        #pragma unroll
        for (int t = 0; t < CIN / 8; ++t) {
            const int ci = t * 8;
            // ---- W tile: 2 coalesced dwordx4 per CPL ----
            f4 w0[CPL], w1[CPL];
            #pragma unroll
            for (int c = 0; c < CPL; ++c) {
                w0[c] = *(const f4*)(Wk + ((size_t)(2 * t) * COUT
                                           + c * 64 + lane) * 4);
                w1[c] = *(const f4*)(Wk + ((size_t)(2 * t + 1) * COUT
                                           + c * 64 + lane) * 4);
            }

            // ---- unguarded batched x s_loads (zrow -> reads 0 if invalid) --
            f4 xv0[R], xv1[R];
            #pragma unroll
            for (int r = 0; r < R; ++r) {
                const float* p;
                if constexpr (CINB > 0)
                    p = (ci < CINA) ? (pA[r] + ci) : (pB[r] + (ci - CINA));
                else
                    p = pA[r] + ci;
                xv0[r] = *(const f4*)p;
                xv1[r] = *(const f4*)(p + 4);
            }

            // ---- guarded FMA blocks (wave-uniform scalar branches) ----
            #pragma unroll
            for (int r = 0; r < R; ++r) {
                if (m[r] >= 0) {
                    #pragma unroll
                    for (int u = 0; u < 4; ++u)
                        #pragma unroll
                        for (int c = 0; c < CPL; ++c) {
                            acc[r][c] = fmaf(xv0[r][u], w0[c][u], acc[r][c]);
                            acc[r][c] = fmaf(xv1[r][u], w1[c][u], acc[r][c]);
                        }
                }
            }
        }
    }

    #pragma unroll
    for (int r = 0; r < R; ++r) {
        const int j = row0 + r;
        if (j < Nout) {
            #pragma unroll
            for (int c = 0; c < CPL; ++c)
                out[(size_t)j * COUT + c * 64 + lane] = acc[r][c];
        }
    }
}

// ---------------------------------------------------------------------------
// conv0: CIN=16, COUT=32. One row per half-wave; block 256 = 8 rows.
// Wt weight loads (dwordx4); zrow-unguarded x (only 1 row / half-wave).
// ---------------------------------------------------------------------------
__global__ __launch_bounds__(256)
void sconv0(const float* __restrict__ x, const float* __restrict__ Wt,
            const int* __restrict__ map, int N, float* __restrict__ out,
            const float* __restrict__ zrow)
{
    const int tid  = threadIdx.x;
    const int lane = tid & 63;
    const int l32  = tid & 31;
    const int co   = l32;
    const int j    = blockIdx.x * 8 + (tid >> 5);

    int mk = (l32 < 27 && j < N) ? map[(size_t)l32 * N + j] : -1;

    float a0 = 0.f, a1 = 0.f, a2 = 0.f, a3 = 0.f;
    for (int k = 0; k < 27; ++k) {
        const int m = __shfl(mk, (lane & 32) + k);
        if (__ballot(m >= 0) == 0ull) continue;
        const float* xr = (m >= 0) ? (x + (size_t)m * 16) : zrow;
        const float* wk = Wt + (size_t)k * 16 * 32;
        f4 w0 = *(const f4*)(wk + (0 * 32 + co) * 4);
        f4 w1 = *(const f4*)(wk + (1 * 32 + co) * 4);
        f4 w2 = *(const f4*)(wk + (2 * 32 + co) * 4);
        f4 w3 = *(const f4*)(wk + (3 * 32 + co) * 4);
        f4 x0 = *(const f4*)(xr);
        f4 x1 = *(const f4*)(xr + 4);
        f4 x2 = *(const f4*)(xr + 8);
        f4 x3 = *(const f4*)(xr + 12);
        #pragma unroll
        for (int u = 0; u < 4; ++u) {
            a0 = fmaf(x0[u], w0[u], a0);
            a1 = fmaf(x1[u], w1[u], a1);
            a2 = fmaf(x2[u], w2[u], a2);
            a3 = fmaf(x3[u], w3[u], a3);
        }
    }
    if (j < N) out[(size_t)j * 32 + co] = (a0 + a1) + (a2 + a3);
}

// ---------------------------------------------------------------------------
// conv0t: x = concat(d1[*,64], s1[*,32]), COUT=2. 32 lanes cooperate per row.
// ---------------------------------------------------------------------------
__global__ __launch_bounds__(256)
void sconv0t(const float* __restrict__ d1, const float* __restrict__ s1,
             const float* __restrict__ W /*[27,96,2]*/,
             const int* __restrict__ map, int N, float* __restrict__ out,
             const float* __restrict__ zrow)
{
    const int tid  = threadIdx.x;
    const int lane = tid & 63;
    const int l32  = tid & 31;
    const int j    = blockIdx.x * 8 + (tid >> 5);

    int mk = (l32 < 27 && j < N) ? map[(size_t)l32 * N + j] : -1;

    float a0 = 0.f, a1 = 0.f;
    for (int k = 0; k < 27; ++k) {
        const int m = __shfl(mk, (lane & 32) + k);
        if (__ballot(m >= 0) == 0ull) continue;
        const float* p1 = (m >= 0) ? (d1 + (size_t)m * 64) : zrow;
        const float* p2 = (m >= 0) ? (s1 + (size_t)m * 32) : zrow;
        const float* w = W + (size_t)k * 96 * 2;
        const float x0 = p1[l32];
        const float x1 = p1[l32 + 32];
        const float x2 = p2[l32];
        a0 = fmaf(x0, w[l32 * 2 + 0], a0);
        a1 = fmaf(x0, w[l32 * 2 + 1], a1);
        a0 = fmaf(x1, w[(l32 + 32) * 2 + 0], a0);
        a1 = fmaf(x1, w[(l32 + 32) * 2 + 1], a1);
        a0 = fmaf(x2, w[(l32 + 64) * 2 + 0], a0);
        a1 = fmaf(x2, w[(l32 + 64) * 2 + 1], a1);
    }
    #pragma unroll
    for (int off = 1; off < 32; off <<= 1) {
        a0 += __shfl_xor(a0, off, 32);
        a1 += __shfl_xor(a1, off, 32);
    }
    if (l32 == 0 && j < N) {
        out[(size_t)j * 2 + 0] = a0;
        out[(size_t)j * 2 + 1] = a1;
    }
}

// ---------------------------------------------------------------------------
// BN pass 1: per-channel sum and sum-of-squares -> atomicAdd into sums[2*C]
// ---------------------------------------------------------------------------
template<int C>
__global__ __launch_bounds__(256)
void bn_reduce_kernel(const float* __restrict__ x, int N,
                      float* __restrict__ sums)
{
    constexpr int RG = 256 / C;
    const int tid = threadIdx.x;
    const int c   = tid % C;
    const int rg  = tid / C;
    float s = 0.f, s2 = 0.f;
    for (int j = blockIdx.x * RG + rg; j < N; j += gridDim.x * RG) {
        const float v = x[(size_t)j * C + c];
        s += v;
        s2 += v * v;
    }
    __shared__ float sh[2 * 256];
    sh[tid] = s;
    sh[256 + tid] = s2;
    __syncthreads();
    for (int stride = 128; stride >= C; stride >>= 1) {
        if (tid < stride) {
            sh[tid] += sh[tid + stride];
            sh[256 + tid] += sh[256 + tid + stride];
        }
        __syncthreads();
    }
    if (tid < C) {
        atomicAdd(&sums[c], sh[tid]);
        atomicAdd(&sums[C + c], sh[256 + tid]);
    }
}

// ---------------------------------------------------------------------------
// BN pass 2: x = relu((x - mu) * rsqrt(var + eps) * g + b), in place
// ---------------------------------------------------------------------------
template<int C>
__global__ __launch_bounds__(256)
void bn_apply_kernel(float* __restrict__ x, int N,
                     const float* __restrict__ sums,
                     const float* __restrict__ g, const float* __restrict__ b)
{
    const int tid = blockIdx.x * blockDim.x + threadIdx.x;
    const int c = tid % C;
    const float invN = 1.0f / (float)N;
    const float mean = sums[c] * invN;
    float var = sums[C + c] * invN - mean * mean;
    var = fmaxf(var, 0.f);
    const float sc = g[c] * rsqrtf(var + BN_EPS);
    const float sh = b[c] - mean * sc;
    const int rows_stride = (gridDim.x * blockDim.x) / C;
    for (int j = tid / C; j < N; j += rows_stride) {
        const size_t i = (size_t)j * C + c;
        const float v = fmaf(x[i], sc, sh);
        x[i] = v > 0.f ? v : 0.f;
    }
}

// ---------------------------------------------------------------------------
extern "C" void kernel_launch(void* const* d_in, const int* in_sizes, int n_in,
                              void* d_out, int out_size, void* d_ws, size_t ws_size,
                              hipStream_t stream)
{
    const float* feats = (const float*)d_in[0];
    const float* W0  = (const float*)d_in[1];
    const float* g0  = (const float*)d_in[2];
    const float* b0  = (const float*)d_in[3];
    const float* W1  = (const float*)d_in[4];
    const float* g1  = (const float*)d_in[5];
    const float* b1  = (const float*)d_in[6];
    const float* W2  = (const float*)d_in[7];
    const float* g2  = (const float*)d_in[8];
    const float* b2  = (const float*)d_in[9];
    const float* W2t = (const float*)d_in[10];
    const float* g2t = (const float*)d_in[11];
    const float* b2t = (const float*)d_in[12];
    const float* W1t = (const float*)d_in[13];
    const float* g1t = (const float*)d_in[14];
    const float* b1t = (const float*)d_in[15];
    const float* W0t = (const float*)d_in[16];
    const int* map0  = (const int*)d_in[17];
    const int* map1  = (const int*)d_in[18];
    const int* map2  = (const int*)d_in[19];
    const int* map2t = (const int*)d_in[20];
    const int* map1t = (const int*)d_in[21];
    const int* map0t = (const int*)d_in[22];

    const int N0 = in_sizes[0] / 16;
    const int N1 = in_sizes[18] / 27;
    const int N2 = in_sizes[19] / 27;

    float* ws = (float*)d_ws;
    float* y0 = ws;                      // [N0,32]  s1
    float* y1 = y0 + (size_t)N0 * 32;    // [N1,64]  s2
    float* y2 = y1 + (size_t)N1 * 64;    // [N2,128] s4
    float* y3 = y2 + (size_t)N2 * 128;   // [N1,64]  d2
    float* y4 = y3 + (size_t)N1 * 64;    // [N0,64]  d1
    float* sums  = y4 + (size_t)N0 * 64; // BN accumulators (704 floats)
    float* sums0 = sums;        // 2*32
    float* sums1 = sums + 64;   // 2*64
    float* sums2 = sums + 192;  // 2*128
    float* sums3 = sums + 448;  // 2*64
    float* sums4 = sums + 576;  // 2*64
    float* zrow  = sums + 704;  // 128 zeroed floats
    // transposed weights
    float* Wt0  = zrow + 128;                   // 27*16*32
    float* Wt1  = Wt0 + 27 * 16 * 32;           // 27*32*64
    float* Wt2  = Wt1 + 27 * 32 * 64;           // 27*64*128
    float* Wt2t = Wt2 + 27 * 64 * 128;          // 27*128*64
    float* Wt1t = Wt2t + 27 * 128 * 64;         // 27*128*64

    hipMemsetAsync(sums, 0, (704 + 128) * sizeof(float), stream);

    // weight transposes (tiny)
    wtrans<16, 32><<<(27 * 4 * 32 + 255) / 256, 256, 0, stream>>>(W0, Wt0);
    wtrans<32, 64><<<(27 * 8 * 64 + 255) / 256, 256, 0, stream>>>(W1, Wt1);
    wtrans<64, 128><<<(27 * 16 * 128 + 255) / 256, 256, 0, stream>>>(W2, Wt2);
    wtrans<128, 64><<<(27 * 32 * 64 + 255) / 256, 256, 0, stream>>>(W2t, Wt2t);
    wtrans<128, 64><<<(27 * 32 * 64 + 255) / 256, 256, 0, stream>>>(W1t, Wt1t);

    // block0: feats[N0,16] -> y0[N0,32]
    sconv0<<<(N0 + 7) / 8, 256, 0, stream>>>(feats, Wt0, map0, N0, y0, zrow);
    bn_reduce_kernel<32><<<256, 256, 0, stream>>>(y0, N0, sums0);
    bn_apply_kernel<32><<<512, 256, 0, stream>>>(y0, N0, sums0, g0, b0);

    // block1: s1[N0,32] -> y1[N1,64]   (R=8 -> 32 rows/block)
    sconv_big<32, 32, 64><<<(N1 + 31) / 32, 256, 0, stream>>>(
        y0, nullptr, Wt1, map1, N1, y1, zrow);
    bn_reduce_kernel<64><<<256, 256, 0, stream>>>(y1, N1, sums1);
    bn_apply_kernel<64><<<512, 256, 0, stream>>>(y1, N1, sums1, g1, b1);

    // block2: s2[N1,64] -> y2[N2,128]
    sconv_big<64, 64, 128><<<(N2 + 31) / 32, 256, 0, stream>>>(
        y1, nullptr, Wt2, map2, N2, y2, zrow);
    bn_reduce_kernel<128><<<256, 256, 0, stream>>>(y2, N2, sums2);
    bn_apply_kernel<128><<<512, 256, 0, stream>>>(y2, N2, sums2, g2, b2);

    // block2_tr: s4[N2,128] -> y3[N1,64]
    sconv_big<128, 128, 64><<<(N1 + 31) / 32, 256, 0, stream>>>(
        y2, nullptr, Wt2t, map2t, N1, y3, zrow);
    bn_reduce_kernel<64><<<256, 256, 0, stream>>>(y3, N1, sums3);
    bn_apply_kernel<64><<<512, 256, 0, stream>>>(y3, N1, sums3, g2t, b2t);

    // block1_tr: concat(d2,s2)[N1,128] -> y4[N0,64]
    sconv_big<128, 64, 64><<<(N0 + 31) / 32, 256, 0, stream>>>(
        y3, y1, Wt1t, map1t, N0, y4, zrow);
    bn_reduce_kernel<64><<<256, 256, 0, stream>>>(y4, N0, sums4);
    bn_apply_kernel<64><<<512, 256, 0, stream>>>(y4, N0, sums4, g1t, b1t);

    // block0_tr: concat(d1,s1)[N0,96] -> out[N0,2]
    sconv0t<<<(N0 + 7) / 8, 256, 0, stream>>>(y4, y0, W0t, map0t, N0,
                                              (float*)d_out, zrow);
}